// Round 2
// baseline (744.597 us; speedup 1.0000x reference)
//
#include <hip/hip_runtime.h>
#include <math.h>

// Problem constants
#define NPIX   131072      // 32*64*64 pixels
#define KCODES 512
#define DIM    64
#define HW     4096        // 64*64
#define CHW    262144      // 64*4096
#define NBLK   1024

// Output layout (floats, concatenated in reference return order)
#define O_Q    1ll
#define O_PERP 8388609ll
#define O_ENC  8388610ll
#define O_IDX  75497474ll

// ws layout (floats): [0] loss accum, [1..512] counts (u32), [513..1024] esq,
//                     [1025] completion ticket (u32)

// Replicate numpy pairwise_sum of x**2 for n=64 (8 accs, stride-8, pairwise combine).
__device__ __forceinline__ float np_sumsq64(const float (&x)[64]) {
#pragma clang fp contract(off)
  float r0 = x[0]*x[0], r1 = x[1]*x[1], r2 = x[2]*x[2], r3 = x[3]*x[3];
  float r4 = x[4]*x[4], r5 = x[5]*x[5], r6 = x[6]*x[6], r7 = x[7]*x[7];
#pragma unroll
  for (int i = 8; i < 64; i += 8) {
    r0 += x[i+0]*x[i+0];
    r1 += x[i+1]*x[i+1];
    r2 += x[i+2]*x[i+2];
    r3 += x[i+3]*x[i+3];
    r4 += x[i+4]*x[i+4];
    r5 += x[i+5]*x[i+5];
    r6 += x[i+6]*x[i+6];
    r7 += x[i+7]*x[i+7];
  }
  return ((r0+r1)+(r2+r3))+((r4+r5)+(r6+r7));
}

// Prep: zero loss accumulator + counts + ticket, compute esq[k] into ws.
__global__ void vq_prep(const float* __restrict__ emb, float* __restrict__ ws) {
  const int t = threadIdx.x;  // 512 threads
  if (t == 0) { ws[0] = 0.0f; ((unsigned*)ws)[1025] = 0u; }
  ((unsigned*)ws)[1 + t] = 0u;
  float x[64];
  const float* e = emb + t * DIM;
#pragma unroll
  for (int d = 0; d < 64; ++d) x[d] = e[d];
  ws[513 + t] = np_sumsq64(x);
}

// --- inlined helpers (all constant-fold when g is compile-time-ish) ---

__device__ __forceinline__ void et_prefetch(const float* __restrict__ emb,
                                            int g, int ec, int eh,
                                            float4& p0, float4& p1) {
  // slice g: codes 256*(g>>2)+ec, dims 16*(g&3) + 8*eh .. +7
  const float* er = emb + (size_t)(256 * (g >> 2) + ec) * 64
                        + 16 * (g & 3) + 8 * eh;
  p0 = *(const float4*)(er + 0);
  p1 = *(const float4*)(er + 4);
}

__device__ __forceinline__ void et_write(float* __restrict__ ETb,
                                         const float4& p0, const float4& p1,
                                         int eh, int ec) {
  const float tmp[8] = {p0.x, p0.y, p0.z, p0.w, p1.x, p1.y, p1.z, p1.w};
#pragma unroll
  for (int dl = 0; dl < 8; ++dl) ETb[(8 * eh + dl) * 256 + ec] = tmp[dl];
}

__device__ __forceinline__ void enc_zero(float2* __restrict__ encb, int g, int t) {
  const float2 zz = make_float2(0.0f, 0.0f);
#pragma unroll
  for (int u = 0; u < 8; ++u)
    encb[(size_t)g * 4096 + u * 512 + t] = zz;
}

__device__ __forceinline__ void dl_loop(const float* __restrict__ ETb,
                                        const float* __restrict__ zl,
                                        int sdim, int pi, int ci,
                                        float (&acc)[8][8]) {
#pragma unroll 2
  for (int dl = 0; dl < 16; ++dl) {
    const float* zp = &zl[(sdim + dl) * 128 + 8 * pi];
    const float4 za0 = *(const float4*)(zp + 0);
    const float4 za1 = *(const float4*)(zp + 4);
    const float* ep = &ETb[dl * 256 + 4 * ci];
    const float4 e0 = *(const float4*)(ep + 0);     // codes 256H+4ci+0..3
    const float4 e1 = *(const float4*)(ep + 128);   // codes 256H+128+4ci..
    const float zr[8] = {za0.x, za0.y, za0.z, za0.w,
                         za1.x, za1.y, za1.z, za1.w};
    const float er_[8] = {e0.x, e0.y, e0.z, e0.w,
                          e1.x, e1.y, e1.z, e1.w};
#pragma unroll
    for (int j = 0; j < 8; ++j)
#pragma unroll
      for (int c = 0; c < 8; ++c)
        acc[j][c] = fmaf(zr[j], er_[c], acc[j][c]);
  }
}

__device__ __forceinline__ void dist_phase(int Hh, int ci, int pi,
                                           const float (&acc)[8][8],
                                           const float* __restrict__ esq_l,
                                           const float* __restrict__ zsq_l,
                                           float (&bd)[8], int (&bk)[8]) {
  // ascending (q,r) = ascending k; strict < == np.argmin semantics.
#pragma unroll
  for (int q = 0; q < 2; ++q)
#pragma unroll
    for (int r = 0; r < 4; ++r) {
      const int k = 256 * Hh + 128 * q + 4 * ci + r;
      const float eq = esq_l[k];
#pragma unroll
      for (int j = 0; j < 8; ++j) {
        const float dist = (zsq_l[8 * pi + j] + eq) - 2.0f * acc[j][4 * q + r];
        if (dist < bd[j]) { bd[j] = dist; bk[j] = k; }
      }
    }
}

// Main: round-9 barrier-halving + fin fusion.
// 512 threads = 128 px x 512 codes per block, grid 1024. Per-thread tile is
// unchanged (8px x 8codes, acc=64 regs); dist math bit-identical to all
// passing rounds: ascending-d fmaf chain, (zsq+esq)-2*dot, ascending-k scan,
// strict <, butterfly tie-break to lower k == np.argmin exactly.
// New vs round 8:
//  (a) ET double-buffer (ET_s[2]) -> ONE barrier per slice (8 in-loop
//      barriers instead of 16), and the ds_writes of the next slice retire
//      ~2000cyc before the barrier that publishes them, so the barrier's
//      lgkmcnt/vmcnt drain is off the critical path. Pipeline: body g writes
//      slice g+1 into buf[(g+1)&1] (regs prefetched in body g-1), prefetches
//      slice g+2, streams one enc-zero batch, runs 16-dl FMA on buf[g&1].
//      Write/read of each buffer are separated by exactly one barrier.
//  (b) vq_fin fused into vq_main: after per-block atomics, threadfence +
//      barrier + ticket atomicAdd; 1024th block re-reads counts/loss via
//      device-scope atomic RMWs (coherent across XCDs) and runs the exact
//      vq_fin reduction. Saves one launch + a 1-block kernel.
// LDS ~68.6KB -> 2 blocks/CU; __launch_bounds__(512,4) keeps <=128 VGPR ->
// 4 waves/SIMD.
__global__ __launch_bounds__(512, 4)
void vq_main(
    const float* __restrict__ z, const float* __restrict__ emb,
    float* __restrict__ out, float* __restrict__ ws)
{
  __shared__ float ET_s[2][16 * 256];  // 32KB: double-buffered 16-d ET slices
  __shared__ float z_l[64 * 128];      // 32KB: z_l[d][px]
  __shared__ float esq_l[512];
  __shared__ float zsq_l[128];
  __shared__ int   ridx_l[128];
  __shared__ float wsum[8];
  __shared__ unsigned lflag;

  const int t   = threadIdx.x;       // 0..511
  const int ci  = t & 31;
  const int pi  = t >> 5;            // 0..15
  const int blk = blockIdx.x;        // grid = 1024
  const int n0  = blk * 128;         // 128 consecutive pixels (same batch b)
  const int b   = n0 >> 12;
  const int hw0 = n0 & 4095;
  const float* zg = z + (size_t)b * CHW + hw0;

  esq_l[t] = ws[513 + t];

  // Stage z_l[d][px]: 64 rows of 128 floats (coalesced float4 global reads).
  {
    const int i     = t & 31;        // float4 index within row
    const int dbase = t >> 5;        // 0..15
#pragma unroll
    for (int r = 0; r < 4; ++r) {
      const int d = dbase + 16 * r;
      *(float4*)&z_l[d * 128 + 4 * i] = *(const float4*)(zg + (size_t)d * HW + 4 * i);
    }
  }

  const int ec = t & 255;            // code within half
  const int eh = t >> 8;             // 0/1: which 8-d subrow of the slice
  float4 p0, p1;
  et_prefetch(emb, 0, ec, eh, p0, p1);   // slice 0; overlaps z-stage wait

  __syncthreads();   // B0: z_l, esq_l ready

  // Exact per-pixel zsq (np pairwise pattern), one thread per pixel.
  if (t < 128) {
    float x[64];
#pragma unroll
    for (int d = 0; d < 64; ++d) x[d] = z_l[d * 128 + t];
    zsq_l[t] = np_sumsq64(x);
  }

  et_write(&ET_s[0][0], p0, p1, eh, ec);  // slice 0 -> buf0
  et_prefetch(emb, 1, ec, eh, p0, p1);    // slice 1

  __syncthreads();   // B1: buf0 + zsq_l ready

  float bd[8];
  int   bk[8];
#pragma unroll
  for (int j = 0; j < 8; ++j) { bd[j] = INFINITY; bk[j] = 0; }
  float acc[8][8];
#pragma unroll
  for (int j = 0; j < 8; ++j)
#pragma unroll
    for (int c = 0; c < 8; ++c) acc[j][c] = 0.0f;

  float2* encb = (float2*)(out + O_ENC) + (size_t)n0 * 256;  // 8B-aligned

  // Main pipeline: slices g=0..7 (g>>2 = code-half H, g&3 = dim-slice s).
  // One barrier per slice; p holds slice g+1 at the top of body g.
  for (int gg = 0; gg < 4; ++gg) {
    {  // ---- even slice ge = 2gg: compute from buf0, fill buf1 ----
      const int ge = 2 * gg;
      et_write(&ET_s[1][0], p0, p1, eh, ec);        // slice ge+1 -> buf1
      if (ge < 6) et_prefetch(emb, ge + 2, ec, eh, p0, p1);
      enc_zero(encb, ge, t);
      dl_loop(&ET_s[0][0], z_l, 16 * (ge & 3), pi, ci, acc);
      __syncthreads();
    }
    {  // ---- odd slice go = 2gg+1: compute from buf1, fill buf0 ----
      const int go = 2 * gg + 1;
      if (go < 7) {
        et_write(&ET_s[0][0], p0, p1, eh, ec);      // slice go+1 -> buf0
        et_prefetch(emb, go + 2, ec, eh, p0, p1);
      }
      enc_zero(encb, go, t);
      dl_loop(&ET_s[1][0], z_l, 16 * (go & 3), pi, ci, acc);
      if (gg & 1) {                                 // go==3 (H0) or go==7 (H1)
        dist_phase(gg >> 1, ci, pi, acc, esq_l, zsq_l, bd, bk);
        if (gg == 1) {
#pragma unroll
          for (int j = 0; j < 8; ++j)
#pragma unroll
            for (int c = 0; c < 8; ++c) acc[j][c] = 0.0f;
        }
      }
      __syncthreads();
    }
  }

  // Butterfly merge across the 32 ci-lanes (tie-break: lower k), exact.
#pragma unroll
  for (int m = 16; m >= 1; m >>= 1) {
#pragma unroll
    for (int j = 0; j < 8; ++j) {
      const float od = __shfl_xor(bd[j], m, 64);
      const int   ok = __shfl_xor(bk[j], m, 64);
      if (od < bd[j] || (od == bd[j] && ok < bk[j])) { bd[j] = od; bk[j] = ok; }
    }
  }
  if (ci == 0) {
#pragma unroll
    for (int j = 0; j < 8; ++j) ridx_l[8 * pi + j] = bk[j];
  }
  __syncthreads();  // publishes ridx_l (enc zeros drained at loop-final barrier)

  // ---- epilogue (all 8 waves) ----
  if (t < 128) {
    const int k = ridx_l[t];
    out[O_IDX + n0 + t] = (float)k;
    atomicAdd((unsigned*)ws + 1 + k, 1u);
    // One-hot scatter: zero at this slot is already globally complete.
    out[O_ENC + (size_t)(n0 + t) * 512 + k] = 1.0f;
  }

  // quantized (transposed back to [B,C,H,W]) + loss, distributed: thread
  // (px = t&127, dq = t>>7) handles 16 d's of one pixel; stores coalesced.
  {
    const int px = t & 127;
    const int dq = t >> 7;
    const int k  = ridx_l[px];
    const float* e0 = emb + ((size_t)k << 6);
    float* q0 = out + O_Q + (size_t)b * CHW + hw0 + px;
    float lsum = 0.0f;
#pragma unroll
    for (int j = 0; j < 16; ++j) {
      const int d = dq * 16 + j;
      const float ev = e0[d];
      const float df = ev - z_l[d * 128 + px];
      lsum = fmaf(df, df, lsum);
      q0[(size_t)d * HW] = ev;
    }
#pragma unroll
    for (int off = 32; off > 0; off >>= 1) lsum += __shfl_down(lsum, off, 64);
    if ((t & 63) == 0) wsum[t >> 6] = lsum;
  }
  __syncthreads();
  if (t == 0)
    atomicAdd(ws, ((wsum[0] + wsum[1]) + (wsum[2] + wsum[3])) +
                  ((wsum[4] + wsum[5]) + (wsum[6] + wsum[7])));

  // ---- fused finalize: release-ticket; last block computes perp + loss ----
  __threadfence();          // all this block's atomics visible before ticket
  __syncthreads();
  if (t == 0) {
    const unsigned old = atomicAdd((unsigned*)ws + 1025, 1u);
    lflag = (old == (unsigned)(NBLK - 1)) ? 1u : 0u;
  }
  __syncthreads();
  if (lflag) {
    // Re-read counts/loss via device-scope atomic RMWs (XCD-coherent).
    // Reduction arithmetic identical to the old vq_fin.
    const float p = (float)atomicAdd((unsigned*)ws + 1 + t, 0u)
                    * (1.0f / 131072.0f);
    float h = p * logf(p + 1e-10f);
#pragma unroll
    for (int off = 32; off > 0; off >>= 1) h += __shfl_down(h, off, 64);
    if ((t & 63) == 0) wsum[t >> 6] = h;
    __syncthreads();
    if (t == 0) {
      float Hs = 0.0f;
#pragma unroll
      for (int w = 0; w < 8; ++w) Hs += wsum[w];
      out[O_PERP] = expf(-Hs);
      out[0] = 1.25f * atomicAdd(ws, 0.0f) * (1.0f / 8388608.0f);
    }
  }
}

extern "C" void kernel_launch(void* const* d_in, const int* in_sizes, int n_in,
                              void* d_out, int out_size, void* d_ws, size_t ws_size,
                              hipStream_t stream) {
  const float* z   = (const float*)d_in[0];
  const float* emb = (const float*)d_in[1];
  float* out = (float*)d_out;
  float* ws  = (float*)d_ws;

  vq_prep<<<1, 512, 0, stream>>>(emb, ws);
  vq_main<<<NBLK, 512, 0, stream>>>(z, emb, out, ws);
}

// Round 3
// 437.262 us; speedup vs baseline: 1.7029x; 1.7029x over previous
//
#include <hip/hip_runtime.h>
#include <math.h>

// Problem constants
#define NPIX   131072      // 32*64*64 pixels
#define KCODES 512
#define DIM    64
#define HW     4096        // 64*64
#define CHW    262144      // 64*4096
#define NBLK   1024

// Output layout (floats, concatenated in reference return order)
#define O_Q    1ll
#define O_PERP 8388609ll
#define O_ENC  8388610ll
#define O_IDX  75497474ll

// ws layout (floats): [0] loss accum, [1..512] counts (u32), [513..1024] esq

// Replicate numpy pairwise_sum of x**2 for n=64 (8 accs, stride-8, pairwise combine).
__device__ __forceinline__ float np_sumsq64(const float (&x)[64]) {
#pragma clang fp contract(off)
  float r0 = x[0]*x[0], r1 = x[1]*x[1], r2 = x[2]*x[2], r3 = x[3]*x[3];
  float r4 = x[4]*x[4], r5 = x[5]*x[5], r6 = x[6]*x[6], r7 = x[7]*x[7];
#pragma unroll
  for (int i = 8; i < 64; i += 8) {
    r0 += x[i+0]*x[i+0];
    r1 += x[i+1]*x[i+1];
    r2 += x[i+2]*x[i+2];
    r3 += x[i+3]*x[i+3];
    r4 += x[i+4]*x[i+4];
    r5 += x[i+5]*x[i+5];
    r6 += x[i+6]*x[i+6];
    r7 += x[i+7]*x[i+7];
  }
  return ((r0+r1)+(r2+r3))+((r4+r5)+(r6+r7));
}

// Prep: zero loss accumulator + counts, compute esq[k] (np-pairwise) into ws.
__global__ void vq_prep(const float* __restrict__ emb, float* __restrict__ ws) {
  const int t = threadIdx.x;  // 512 threads
  if (t == 0) ws[0] = 0.0f;
  ((unsigned*)ws)[1 + t] = 0u;
  float x[64];
  const float* e = emb + t * DIM;
#pragma unroll
  for (int d = 0; d < 64; ++d) x[d] = e[d];
  ws[513 + t] = np_sumsq64(x);
}

// --- inlined helpers ---

__device__ __forceinline__ void et_prefetch(const float* __restrict__ emb,
                                            int g, int ec, int eh,
                                            float4& p0, float4& p1) {
  // slice g: codes 256*(g>>2)+ec, dims 16*(g&3) + 8*eh .. +7
  const float* er = emb + (size_t)(256 * (g >> 2) + ec) * 64
                        + 16 * (g & 3) + 8 * eh;
  p0 = *(const float4*)(er + 0);
  p1 = *(const float4*)(er + 4);
}

__device__ __forceinline__ void et_write(float* __restrict__ ETb,
                                         const float4& p0, const float4& p1,
                                         int eh, int ec) {
  const float tmp[8] = {p0.x, p0.y, p0.z, p0.w, p1.x, p1.y, p1.z, p1.w};
#pragma unroll
  for (int dl = 0; dl < 8; ++dl) ETb[(8 * eh + dl) * 256 + ec] = tmp[dl];
}

__device__ __forceinline__ void enc_zero(float2* __restrict__ encb, int g, int t) {
  const float2 zz = make_float2(0.0f, 0.0f);
#pragma unroll
  for (int u = 0; u < 8; ++u)
    encb[(size_t)g * 4096 + u * 512 + t] = zz;
}

__device__ __forceinline__ void dl_loop(const float* __restrict__ ETb,
                                        const float* __restrict__ zl,
                                        int sdim, int pi, int ci,
                                        float (&acc)[8][8]) {
#pragma unroll 2
  for (int dl = 0; dl < 16; ++dl) {
    const float* zp = &zl[(sdim + dl) * 128 + 8 * pi];
    const float4 za0 = *(const float4*)(zp + 0);
    const float4 za1 = *(const float4*)(zp + 4);
    const float* ep = &ETb[dl * 256 + 4 * ci];
    const float4 e0 = *(const float4*)(ep + 0);     // codes 256H+4ci+0..3
    const float4 e1 = *(const float4*)(ep + 128);   // codes 256H+128+4ci..
    const float zr[8] = {za0.x, za0.y, za0.z, za0.w,
                         za1.x, za1.y, za1.z, za1.w};
    const float er_[8] = {e0.x, e0.y, e0.z, e0.w,
                          e1.x, e1.y, e1.z, e1.w};
#pragma unroll
    for (int j = 0; j < 8; ++j)
#pragma unroll
      for (int c = 0; c < 8; ++c)
        acc[j][c] = fmaf(zr[j], er_[c], acc[j][c]);
  }
}

__device__ __forceinline__ void dist_phase(int Hh, int ci, int pi,
                                           const float (&acc)[8][8],
                                           const float* __restrict__ esq_l,
                                           const float* __restrict__ zsq_l,
                                           float (&bd)[8], int (&bk)[8]) {
  // ascending (q,r) = ascending k; strict < == np.argmin semantics.
#pragma unroll
  for (int q = 0; q < 2; ++q)
#pragma unroll
    for (int r = 0; r < 4; ++r) {
      const int k = 256 * Hh + 128 * q + 4 * ci + r;
      const float eq = esq_l[k];
#pragma unroll
      for (int j = 0; j < 8; ++j) {
        const float dist = (zsq_l[8 * pi + j] + eq) - 2.0f * acc[j][4 * q + r];
        if (dist < bd[j]) { bd[j] = dist; bk[j] = k; }
      }
    }
}

// Main: round-10 = round-9 double-buffer MINUS the fin fusion.
// Round-2 post-mortem: the fused finalize's __threadfence() is agent-scope on
// gfx950 -> buffer_wbl2 + s_waitcnt + buffer_inv (full per-XCD L2 writeback +
// invalidate) PER BLOCK x1024 -> vq_main 199->478us, VALUBusy 17%. Removed;
// vq_fin is a separate 1-block launch again (~5-10us, known-good).
// Kept from round 9: ET double-buffer -> ONE barrier per slice (8 in-loop
// barriers vs round-7's 16), ds_writes retire ~2000cyc before the barrier
// that publishes them. Dist math bit-identical to all passing rounds:
// ascending-d fmaf chain, (zsq+esq)-2*dot, ascending-k scan, strict <,
// butterfly tie-break to lower k == np.argmin exactly.
// LDS ~68.6KB -> 2 blocks/CU; __launch_bounds__(512,4) keeps <=128 VGPR ->
// 4 waves/SIMD.
__global__ __launch_bounds__(512, 4)
void vq_main(
    const float* __restrict__ z, const float* __restrict__ emb,
    float* __restrict__ out, float* __restrict__ ws)
{
  __shared__ float ET_s[2][16 * 256];  // 32KB: double-buffered 16-d ET slices
  __shared__ float z_l[64 * 128];      // 32KB: z_l[d][px]
  __shared__ float esq_l[512];
  __shared__ float zsq_l[128];
  __shared__ int   ridx_l[128];
  __shared__ float wsum[8];

  const int t   = threadIdx.x;       // 0..511
  const int ci  = t & 31;
  const int pi  = t >> 5;            // 0..15
  const int blk = blockIdx.x;        // grid = 1024
  const int n0  = blk * 128;         // 128 consecutive pixels (same batch b)
  const int b   = n0 >> 12;
  const int hw0 = n0 & 4095;
  const float* zg = z + (size_t)b * CHW + hw0;

  esq_l[t] = ws[513 + t];

  // Stage z_l[d][px]: 64 rows of 128 floats (coalesced float4 global reads).
  {
    const int i     = t & 31;        // float4 index within row
    const int dbase = t >> 5;        // 0..15
#pragma unroll
    for (int r = 0; r < 4; ++r) {
      const int d = dbase + 16 * r;
      *(float4*)&z_l[d * 128 + 4 * i] = *(const float4*)(zg + (size_t)d * HW + 4 * i);
    }
  }

  const int ec = t & 255;            // code within half
  const int eh = t >> 8;             // 0/1: which 8-d subrow of the slice
  float4 p0, p1;
  et_prefetch(emb, 0, ec, eh, p0, p1);   // slice 0; overlaps z-stage wait

  __syncthreads();   // B0: z_l, esq_l ready

  // Exact per-pixel zsq (np pairwise pattern), one thread per pixel.
  if (t < 128) {
    float x[64];
#pragma unroll
    for (int d = 0; d < 64; ++d) x[d] = z_l[d * 128 + t];
    zsq_l[t] = np_sumsq64(x);
  }

  et_write(&ET_s[0][0], p0, p1, eh, ec);  // slice 0 -> buf0
  et_prefetch(emb, 1, ec, eh, p0, p1);    // slice 1

  __syncthreads();   // B1: buf0 + zsq_l ready

  float bd[8];
  int   bk[8];
#pragma unroll
  for (int j = 0; j < 8; ++j) { bd[j] = INFINITY; bk[j] = 0; }
  float acc[8][8];
#pragma unroll
  for (int j = 0; j < 8; ++j)
#pragma unroll
    for (int c = 0; c < 8; ++c) acc[j][c] = 0.0f;

  float2* encb = (float2*)(out + O_ENC) + (size_t)n0 * 256;  // 8B-aligned

  // Main pipeline: slices g=0..7 (g>>2 = code-half H, g&3 = dim-slice s).
  // One barrier per slice; p holds slice g+1 at the top of body g.
  // Hazard check: body g reads buf[g&1], writes buf[(g+1)&1]; each buffer's
  // write and subsequent read are separated by exactly one barrier.
  for (int gg = 0; gg < 4; ++gg) {
    {  // ---- even slice ge = 2gg: compute from buf0, fill buf1 ----
      const int ge = 2 * gg;
      et_write(&ET_s[1][0], p0, p1, eh, ec);        // slice ge+1 -> buf1
      if (ge < 6) et_prefetch(emb, ge + 2, ec, eh, p0, p1);
      enc_zero(encb, ge, t);
      dl_loop(&ET_s[0][0], z_l, 16 * (ge & 3), pi, ci, acc);
      __syncthreads();
    }
    {  // ---- odd slice go = 2gg+1: compute from buf1, fill buf0 ----
      const int go = 2 * gg + 1;
      if (go < 7) {
        et_write(&ET_s[0][0], p0, p1, eh, ec);      // slice go+1 -> buf0
        et_prefetch(emb, go + 2, ec, eh, p0, p1);
      }
      enc_zero(encb, go, t);
      dl_loop(&ET_s[1][0], z_l, 16 * (go & 3), pi, ci, acc);
      if (gg & 1) {                                 // go==3 (H0) or go==7 (H1)
        dist_phase(gg >> 1, ci, pi, acc, esq_l, zsq_l, bd, bk);
        if (gg == 1) {
#pragma unroll
          for (int j = 0; j < 8; ++j)
#pragma unroll
            for (int c = 0; c < 8; ++c) acc[j][c] = 0.0f;
        }
      }
      __syncthreads();
    }
  }

  // Butterfly merge across the 32 ci-lanes (tie-break: lower k), exact.
#pragma unroll
  for (int m = 16; m >= 1; m >>= 1) {
#pragma unroll
    for (int j = 0; j < 8; ++j) {
      const float od = __shfl_xor(bd[j], m, 64);
      const int   ok = __shfl_xor(bk[j], m, 64);
      if (od < bd[j] || (od == bd[j] && ok < bk[j])) { bd[j] = od; bk[j] = ok; }
    }
  }
  if (ci == 0) {
#pragma unroll
    for (int j = 0; j < 8; ++j) ridx_l[8 * pi + j] = bk[j];
  }
  __syncthreads();  // publishes ridx_l (enc zeros drained at loop-final barrier)

  // ---- epilogue (all 8 waves) ----
  if (t < 128) {
    const int k = ridx_l[t];
    out[O_IDX + n0 + t] = (float)k;
    atomicAdd((unsigned*)ws + 1 + k, 1u);
    // One-hot scatter: zero at this slot is already globally complete.
    out[O_ENC + (size_t)(n0 + t) * 512 + k] = 1.0f;
  }

  // quantized (transposed back to [B,C,H,W]) + loss, distributed: thread
  // (px = t&127, dq = t>>7) handles 16 d's of one pixel; stores coalesced.
  {
    const int px = t & 127;
    const int dq = t >> 7;
    const int k  = ridx_l[px];
    const float* e0 = emb + ((size_t)k << 6);
    float* q0 = out + O_Q + (size_t)b * CHW + hw0 + px;
    float lsum = 0.0f;
#pragma unroll
    for (int j = 0; j < 16; ++j) {
      const int d = dq * 16 + j;
      const float ev = e0[d];
      const float df = ev - z_l[d * 128 + px];
      lsum = fmaf(df, df, lsum);
      q0[(size_t)d * HW] = ev;
    }
#pragma unroll
    for (int off = 32; off > 0; off >>= 1) lsum += __shfl_down(lsum, off, 64);
    if ((t & 63) == 0) wsum[t >> 6] = lsum;
  }
  __syncthreads();
  if (t == 0)
    atomicAdd(ws, ((wsum[0] + wsum[1]) + (wsum[2] + wsum[3])) +
                  ((wsum[4] + wsum[5]) + (wsum[6] + wsum[7])));
}

// Finalize: perplexity from counts (exact: counts/2^17), loss mean.
__global__ void vq_fin(float* __restrict__ out, const float* __restrict__ ws) {
  __shared__ float red[8];
  const int t = threadIdx.x;  // 512
  const unsigned* counts = (const unsigned*)ws + 1;
  const float p = (float)counts[t] * (1.0f / 131072.0f);
  float h = p * logf(p + 1e-10f);
#pragma unroll
  for (int off = 32; off > 0; off >>= 1) h += __shfl_down(h, off, 64);
  if ((t & 63) == 0) red[t >> 6] = h;
  __syncthreads();
  if (t == 0) {
    float H = 0.0f;
#pragma unroll
    for (int w = 0; w < 8; ++w) H += red[w];
    out[O_PERP] = expf(-H);
    out[0] = 1.25f * ws[0] * (1.0f / 8388608.0f);
  }
}

extern "C" void kernel_launch(void* const* d_in, const int* in_sizes, int n_in,
                              void* d_out, int out_size, void* d_ws, size_t ws_size,
                              hipStream_t stream) {
  const float* z   = (const float*)d_in[0];
  const float* emb = (const float*)d_in[1];
  float* out = (float*)d_out;
  float* ws  = (float*)d_ws;

  vq_prep<<<1, 512, 0, stream>>>(emb, ws);
  vq_main<<<NBLK, 512, 0, stream>>>(z, emb, out, ws);
  vq_fin<<<1, 512, 0, stream>>>(out, ws);
}